// Round 3
// baseline (798.432 us; speedup 1.0000x reference)
//
#include <hip/hip_runtime.h>

typedef short bf16x8 __attribute__((ext_vector_type(8)));
typedef short bf16x4 __attribute__((ext_vector_type(4)));
typedef float f32x4 __attribute__((ext_vector_type(4)));
typedef float f32x16 __attribute__((ext_vector_type(16)));
typedef unsigned short u16;
typedef unsigned int u32;
typedef u16 u16x8 __attribute__((ext_vector_type(8)));
typedef u16 u16x4 __attribute__((ext_vector_type(4)));

// Diagnostic round: each kernel repeats its body REP times (idempotent).
// Per-kernel time = dispatch_dur / REP; counters become visible in top-5.
#define REP 16

#define DEV __device__ __forceinline__

DEV u16 f2bf(float f) {
  unsigned u = __float_as_uint(f);
  u += 0x7fff + ((u >> 16) & 1);  // RNE (no NaN in this workload)
  return (u16)(u >> 16);
}

DEV int pkbf(float lo, float hi) {
  return __builtin_amdgcn_perm(__float_as_uint(hi) + 0x8000u,
                               __float_as_uint(lo) + 0x8000u, 0x07060302u);
}

#define MFMA16(a, b, c) __builtin_amdgcn_mfma_f32_16x16x32_bf16(a, b, c, 0, 0, 0)
#define MFMA3216(a, b, c) __builtin_amdgcn_mfma_f32_32x32x16_bf16(a, b, c, 0, 0, 0)

#if __has_builtin(__builtin_amdgcn_mfma_f32_32x32x8bf16_1k)
#define HAVE_PV8 1
#define PVMFMA(a, b, c) __builtin_amdgcn_mfma_f32_32x32x8bf16_1k(a, b, c, 0, 0, 0)
#else
#define HAVE_PV8 0
#endif

#if __has_builtin(__builtin_amdgcn_exp2f)
#define QSCALE 0.18033688011112042f  // 0.125 * log2(e)
#define EXPFN(x) __builtin_amdgcn_exp2f(x)
#else
#define QSCALE 0.125f
#define EXPFN(x) __expf(x)
#endif

#define GLD16(gp, lp)                                                     \
  __builtin_amdgcn_global_load_lds(                                       \
      (const __attribute__((address_space(1))) u32*)(gp),                 \
      (__attribute__((address_space(3))) u32*)(lp), 16, 0, 0)

// ---------------------------------------------------------------------------
// wprep (REP'd): transpose+convert weights; pre-convert x1/x2 to bf16.
// ---------------------------------------------------------------------------
__global__ __launch_bounds__(256) void wprep(
    const float* __restrict__ Wqk, const float* __restrict__ Wv,
    const float* __restrict__ Wout,
    const float* __restrict__ x1, const float* __restrict__ x2,
    u16* __restrict__ WqkT, u16* __restrict__ WvT, u16* __restrict__ WoutT,
    u16* __restrict__ x1b, u16* __restrict__ x2b) {
  __shared__ float tf[32][33];
  int bx = blockIdx.x, t = threadIdx.x;
  if (bx >= 1024) {
    int id = bx - 1024;  // 0..2047
    const float* src = id < 1024 ? x1 : x2;
    u16* dst = id < 1024 ? x1b : x2b;
    long base = (long)(id & 1023) * 2048 + t * 8;
    for (int rep = 0; rep < REP; ++rep) {
      float4 f0 = *(const float4*)(src + base);
      float4 f1 = *(const float4*)(src + base + 4);
      u16x8 o;
      o[0] = f2bf(f0.x); o[1] = f2bf(f0.y); o[2] = f2bf(f0.z); o[3] = f2bf(f0.w);
      o[4] = f2bf(f1.x); o[5] = f2bf(f1.y); o[6] = f2bf(f1.z); o[7] = f2bf(f1.w);
      *(u16x8*)(dst + base) = o;
    }
    return;
  }
  const float* src; u16* dst; int Ncols; int id;
  if (bx < 512)      { id = bx;       src = Wqk;  dst = WqkT;  Ncols = 1024; }
  else if (bx < 768) { id = bx - 512; src = Wv;   dst = WvT;   Ncols = 512; }
  else               { id = bx - 768; src = Wout; dst = WoutT; Ncols = 512; }
  int tilesPerRow = Ncols >> 5;
  int tr = id / tilesPerRow, tc = id % tilesPerRow;
  int r0 = tr * 32, c0 = tc * 32;
  for (int rep = 0; rep < REP; ++rep) {
    {
      int r = t >> 3, c4 = (t & 7) * 4;
      float4 v = *(const float4*)(src + (long)(r0 + r) * Ncols + c0 + c4);
      tf[r][c4] = v.x; tf[r][c4 + 1] = v.y; tf[r][c4 + 2] = v.z; tf[r][c4 + 3] = v.w;
    }
    __syncthreads();
    {
      int c = t >> 3, r4 = (t & 7) * 4;
      u16x4 o;
      o[0] = f2bf(tf[r4][c]); o[1] = f2bf(tf[r4 + 1][c]);
      o[2] = f2bf(tf[r4 + 2][c]); o[3] = f2bf(tf[r4 + 3][c]);
      *(u16x4*)(dst + (long)(c0 + c) * 512 + r0 + r4) = o;
    }
    __syncthreads();  // WAR: next rep rewrites tf
  }
}

// ---------------------------------------------------------------------------
// Fused QKV GEMM (m97-style, REP'd): 128x128 tile, BK=32, GLD16 staging,
// both-sides XOR swizzle. Grid 384.
// ---------------------------------------------------------------------------
__global__ __launch_bounds__(256) void qkv_gemm(
    const u16* __restrict__ x1b, const u16* __restrict__ x2b,
    const u16* __restrict__ WqkT, const u16* __restrict__ WvT,
    u16* __restrict__ out_q, u16* __restrict__ out_k, u16* __restrict__ out_vt) {
  __shared__ u16 sA[2][128 * 32];
  __shared__ u16 sB[2][128 * 32];
  int bx = blockIdx.x, t = threadIdx.x;
  bool isQ = bx < 128;
  int bx2 = isQ ? bx : bx - 128;
  const u16* Ap = isQ ? x2b : x1b;
  const u16* BT = isQ ? WvT : WqkT;
  int m0 = (bx2 & 31) * 128, n0 = (bx2 >> 5) * 128;
  int w = t >> 6, l = t & 63, lm = l & 15, lq = l >> 4;
  int wr = w >> 1, wc = w & 1;

  int srow = w * 16 + (l >> 2);
  int swzk = ((l & 3) ^ ((l >> 3) & 3)) * 8;
  const u16* gAsrc = Ap + (long)(m0 + srow) * 512 + swzk;
  const u16* gBsrc = BT + (long)(n0 + srow) * 512 + swzk;

  auto stage = [&](int kt, int buf) {
    const u16* a0 = gAsrc + kt * 32;
    const u16* b0 = gBsrc + kt * 32;
    GLD16(a0,            sA[buf] + w * 512);
    GLD16(a0 + 64 * 512, sA[buf] + 2048 + w * 512);
    GLD16(b0,            sB[buf] + w * 512);
    GLD16(b0 + 64 * 512, sB[buf] + 2048 + w * 512);
  };

  int rchunk = (lq ^ ((lm >> 1) & 3)) * 8;
  int frA = (wr * 64 + lm) * 32 + rchunk;
  int frB = (wc * 64 + lm) * 32 + rchunk;

  for (int rep = 0; rep < REP; ++rep) {
    f32x4 zero = {0.f, 0.f, 0.f, 0.f};
    f32x4 acc[4][4];
#pragma unroll
    for (int i = 0; i < 4; ++i)
#pragma unroll
      for (int j = 0; j < 4; ++j) acc[i][j] = zero;

    stage(0, 0);
    __syncthreads();

    for (int kt = 0; kt < 16; ++kt) {
      int cur = kt & 1;
      if (kt < 15) stage(kt + 1, cur ^ 1);
      bf16x8 af[4], bfr[4];
#pragma unroll
      for (int ms = 0; ms < 4; ++ms)
        af[ms] = *(const bf16x8*)(sA[cur] + frA + ms * 512);
#pragma unroll
      for (int s = 0; s < 4; ++s)
        bfr[s] = *(const bf16x8*)(sB[cur] + frB + s * 512);
#pragma unroll
      for (int ms = 0; ms < 4; ++ms)
#pragma unroll
        for (int s = 0; s < 4; ++s)
          acc[ms][s] = MFMA16(af[ms], bfr[s], acc[ms][s]);
      __syncthreads();
    }

#pragma unroll
    for (int ms = 0; ms < 4; ++ms) {
      int gmBase = m0 + wr * 64 + ms * 16 + lq * 4;
      int b = gmBase >> 11, n = gmBase & 2047;
#pragma unroll
      for (int s = 0; s < 4; ++s) {
        int gc = n0 + wc * 64 + s * 16 + lm;
        if (isQ) {
#pragma unroll
          for (int r = 0; r < 4; ++r)
            out_q[(((long)(b << 3) + (gc >> 6)) * 2048 + n + r) * 64 + (gc & 63)] =
                f2bf(acc[ms][s][r] * QSCALE);
        } else if (gc < 512) {
#pragma unroll
          for (int r = 0; r < 4; ++r)
            out_k[(((long)(b << 3) + (gc >> 6)) * 2048 + n + r) * 64 + (gc & 63)] =
                f2bf(acc[ms][s][r]);
        } else {
          int c = gc - 512, h = c >> 6, d = c & 63;
          u16x4 vv;
#pragma unroll
          for (int r = 0; r < 4; ++r) vv[r] = f2bf(acc[ms][s][r]);
          *(u16x4*)(out_vt + (((long)(b << 3) + h) * 64 + d) * 2048 + n) = vv;
        }
      }
    }
    __syncthreads();  // quiesce before next rep restages buf 0
  }
}

// ---------------------------------------------------------------------------
// Attention (REP'd): double-buffered DMA staging + tree dacc + setprio.
// ---------------------------------------------------------------------------
__global__ __launch_bounds__(256, 2) void attn(
    const u16* __restrict__ Q, const u16* __restrict__ K,
    const u16* __restrict__ Vt, u16* __restrict__ O) {
  int id = blockIdx.x;
  int bh = id & 15, qt = id >> 4;
  int b = bh >> 3, h = bh & 7;
  const u16* Kh = K + (long)bh * 2048 * 64;
  const u16* Vh = Vt + (long)bh * 64 * 2048;
  int t = threadIdx.x, w = t >> 6, lane = t & 63, ln = lane & 31, hi = lane >> 5;
  int g = w & 1, kh = w >> 1;

  __shared__ u16 smem[2][2][2][4096];  // [buf][K/V][kh][64x64 swizzled]

  bf16x8 qf[4];
  {
    const u16* qp = Q + (long)bh * 2048 * 64 + (long)(qt * 64 + g * 32 + ln) * 64 + hi * 8;
#pragma unroll
    for (int dc = 0; dc < 4; ++dc) qf[dc] = *(const bf16x8*)(qp + dc * 16);
  }

  int lrow = lane >> 3;
  int swz = ((lane & 7) ^ lrow) * 8;
  const u16* gKl = Kh + (long)(kh * 1024 + g * 32 + lrow) * 64 + swz;
  const u16* gVl = Vh + (long)(g * 32 + lrow) * 2048 + kh * 1024 + swz;

  auto stage = [&](int jt, int buf) {
    u16* sK = smem[buf][0][kh];
    u16* sV = smem[buf][1][kh];
    const u16* gk = gKl + (long)jt * 4096;
    const u16* gv = gVl + jt * 64;
#pragma unroll
    for (int i = 0; i < 4; ++i) {
      GLD16(gk + i * 512, sK + (g * 32 + i * 8) * 64);
      GLD16(gv + (long)i * 16384, sV + (g * 32 + i * 8) * 64);
    }
  };

  int swl = ln & 7;

  for (int rep = 0; rep < REP; ++rep) {
    f32x16 accO[2];
#pragma unroll
    for (int dt = 0; dt < 2; ++dt)
#pragma unroll
      for (int i = 0; i < 16; ++i) accO[dt][i] = 0.f;
    float dacc = 0.f;

    stage(0, 0);
    __syncthreads();

    for (int jt = 0; jt < 16; ++jt) {
      int cur = jt & 1;
      if (jt < 15) stage(jt + 1, cur ^ 1);
      const u16* sKh = smem[cur][0][kh];
      const u16* sVh = smem[cur][1][kh];
#pragma unroll
      for (int kt2 = 0; kt2 < 2; ++kt2) {
        int rowK = (kt2 * 32 + ln) * 64;
        f32x16 st1, st2;
#pragma unroll
        for (int i = 0; i < 16; ++i) { st1[i] = 0.f; st2[i] = 0.f; }
        bf16x8 kf0 = *(const bf16x8*)(sKh + rowK + ((0 * 2 + hi) ^ swl) * 8);
        bf16x8 kf1 = *(const bf16x8*)(sKh + rowK + ((1 * 2 + hi) ^ swl) * 8);
        bf16x8 kf2 = *(const bf16x8*)(sKh + rowK + ((2 * 2 + hi) ^ swl) * 8);
        bf16x8 kf3 = *(const bf16x8*)(sKh + rowK + ((3 * 2 + hi) ^ swl) * 8);
        __builtin_amdgcn_s_setprio(1);
        st1 = MFMA3216(kf0, qf[0], st1);
        st2 = MFMA3216(kf1, qf[1], st2);
        st1 = MFMA3216(kf2, qf[2], st1);
        st2 = MFMA3216(kf3, qf[3], st2);
        __builtin_amdgcn_s_setprio(0);
        float p[16];
#pragma unroll
        for (int i = 0; i < 16; ++i) p[i] = EXPFN(st1[i] + st2[i]);
        float q0 = (p[0] + p[1]) + (p[2] + p[3]);
        float q1 = (p[4] + p[5]) + (p[6] + p[7]);
        float q2 = (p[8] + p[9]) + (p[10] + p[11]);
        float q3 = (p[12] + p[13]) + (p[14] + p[15]);
        dacc += (q0 + q1) + (q2 + q3);
#if HAVE_PV8
        __builtin_amdgcn_s_setprio(1);
#pragma unroll
        for (int c = 0; c < 4; ++c) {
          union { int2 i2; bf16x4 v; } u;
          u.i2.x = pkbf(p[c * 4 + 0], p[c * 4 + 1]);
          u.i2.y = pkbf(p[c * 4 + 2], p[c * 4 + 3]);
#pragma unroll
          for (int dt = 0; dt < 2; ++dt) {
            bf16x4 vf = *(const bf16x4*)(sVh + (dt * 32 + ln) * 64 +
                                         (((kt2 * 4 + c) ^ swl) * 8) + hi * 4);
            accO[dt] = PVMFMA(vf, u.v, accO[dt]);
          }
        }
        __builtin_amdgcn_s_setprio(0);
#else
        __builtin_amdgcn_s_setprio(1);
#pragma unroll
        for (int c2 = 0; c2 < 2; ++c2) {
          int o0x = pkbf(p[c2 * 8 + 0], p[c2 * 8 + 1]);
          int o0y = pkbf(p[c2 * 8 + 2], p[c2 * 8 + 3]);
          int o1x = pkbf(p[c2 * 8 + 4], p[c2 * 8 + 5]);
          int o1y = pkbf(p[c2 * 8 + 6], p[c2 * 8 + 7]);
          int s0x = __shfl_xor(o0x, 32), s0y = __shfl_xor(o0y, 32);
          int s1x = __shfl_xor(o1x, 32), s1y = __shfl_xor(o1y, 32);
          union { int4 i4; bf16x8 v; } u;
          if (hi) { u.i4.x = s1x; u.i4.y = s1y; u.i4.z = o1x; u.i4.w = o1y; }
          else    { u.i4.x = o0x; u.i4.y = o0y; u.i4.z = s0x; u.i4.w = s0y; }
#pragma unroll
          for (int dt = 0; dt < 2; ++dt) {
            bf16x8 vf = *(const bf16x8*)(sVh + (dt * 32 + ln) * 64 +
                                         (((kt2 * 4 + c2 * 2 + hi) ^ swl) * 8));
            accO[dt] = MFMA3216(vf, u.v, accO[dt]);
          }
        }
        __builtin_amdgcn_s_setprio(0);
#endif
      }
      __syncthreads();
    }

    // combine key-halves via LDS scratch (aliases smem buf0)
    float* cb = (float*)&smem[0][0][0][0];
    float* base = cb + g * 2112;
    if (kh == 1) {
#pragma unroll
      for (int dt = 0; dt < 2; ++dt)
#pragma unroll
        for (int i = 0; i < 16; ++i)
          base[(dt * 16 + i) * 64 + hi * 32 + ln] = accO[dt][i];
      base[2048 + hi * 32 + ln] = dacc;
    }
    __syncthreads();
    if (kh == 0) {
#pragma unroll
      for (int dt = 0; dt < 2; ++dt)
#pragma unroll
        for (int i = 0; i < 16; ++i)
          accO[dt][i] += base[(dt * 16 + i) * 64 + hi * 32 + ln];
      dacc += base[2048 + hi * 32 + ln];
      dacc += __shfl_xor(dacc, 32);
      float inv = 1.f / dacc;

      u16* Ob = O + ((long)b * 2048 + qt * 64 + g * 32 + ln) * 512 + h * 64;
#pragma unroll
      for (int dt = 0; dt < 2; ++dt)
#pragma unroll
        for (int gq = 0; gq < 4; ++gq) {
          u16x4 o;
#pragma unroll
          for (int rr = 0; rr < 4; ++rr) o[rr] = f2bf(accO[dt][gq * 4 + rr] * inv);
          *(u16x4*)(Ob + dt * 32 + gq * 8 + hi * 4) = o;
        }
    }
    __syncthreads();  // scratch (buf0) quiesced before next rep's stage(0,0)
  }
}

// ---------------------------------------------------------------------------
// out GEMM v3 (REP'd): BM=64, BN=128 -> 256 blocks (1/CU, fixes round-2's
// half-idle 128-block grid). 4 waves, wave-tile 32x64, GLD16 + swizzle.
// ---------------------------------------------------------------------------
__global__ __launch_bounds__(256) void out_gemm(
    const u16* __restrict__ A, const u16* __restrict__ BT,
    float* __restrict__ out_f, const float* __restrict__ bias) {
  __shared__ u16 sA[2][64 * 32];
  __shared__ u16 sB[2][128 * 32];
  int bx = blockIdx.x, t = threadIdx.x;
  int m0 = (bx & 63) * 64, n0 = (bx >> 6) * 128;
  int w = t >> 6, l = t & 63, lm = l & 15, lq = l >> 4;
  int wr = w >> 1, wc = w & 1;

  int srow = l >> 2;
  int swzk = ((l & 3) ^ ((l >> 3) & 3)) * 8;
  const u16* gAsrc = A + (long)(m0 + w * 16 + srow) * 512 + swzk;
  const u16* gBsrc = BT + (long)(n0 + w * 32 + srow) * 512 + swzk;

  auto stage = [&](int kt, int buf) {
    GLD16(gAsrc + kt * 32,            sA[buf] + w * 512);
    GLD16(gBsrc + kt * 32,            sB[buf] + w * 1024);
    GLD16(gBsrc + 16 * 512 + kt * 32, sB[buf] + w * 1024 + 512);
  };

  int rchunk = (lq ^ ((lm >> 1) & 3)) * 8;
  int frA = (wr * 32 + lm) * 32 + rchunk;
  int frB = (wc * 64 + lm) * 32 + rchunk;

  for (int rep = 0; rep < REP; ++rep) {
    f32x4 zero = {0.f, 0.f, 0.f, 0.f};
    f32x4 acc[2][4];
#pragma unroll
    for (int i = 0; i < 2; ++i)
#pragma unroll
      for (int j = 0; j < 4; ++j) acc[i][j] = zero;

    stage(0, 0);
    __syncthreads();

    for (int kt = 0; kt < 16; ++kt) {
      int cur = kt & 1;
      if (kt < 15) stage(kt + 1, cur ^ 1);
      bf16x8 af[2], bfr[4];
#pragma unroll
      for (int ms = 0; ms < 2; ++ms)
        af[ms] = *(const bf16x8*)(sA[cur] + frA + ms * 512);
#pragma unroll
      for (int s = 0; s < 4; ++s)
        bfr[s] = *(const bf16x8*)(sB[cur] + frB + s * 512);
#pragma unroll
      for (int ms = 0; ms < 2; ++ms)
#pragma unroll
        for (int s = 0; s < 4; ++s)
          acc[ms][s] = MFMA16(af[ms], bfr[s], acc[ms][s]);
      __syncthreads();
    }

#pragma unroll
    for (int ms = 0; ms < 2; ++ms) {
      int gm = m0 + wr * 32 + ms * 16 + lq * 4;
#pragma unroll
      for (int s = 0; s < 4; ++s) {
        int gc = n0 + wc * 64 + s * 16 + lm;
        float bv = bias[gc];
#pragma unroll
        for (int r = 0; r < 4; ++r)
          out_f[(long)(gm + r) * 512 + gc] = acc[ms][s][r] + bv;
      }
    }
    __syncthreads();
  }
}

// ---------------------------------------------------------------------------
extern "C" void kernel_launch(void* const* d_in, const int* in_sizes, int n_in,
                              void* d_out, int out_size, void* d_ws, size_t ws_size,
                              hipStream_t stream) {
  const float* x1 = (const float*)d_in[0];
  const float* x2 = (const float*)d_in[1];
  const float* Wqk = (const float*)d_in[2];
  const float* Wv = (const float*)d_in[3];
  const float* Wout = (const float*)d_in[4];
  const float* bout = (const float*)d_in[5];
  float* out = (float*)d_out;

  u16* ws = (u16*)d_ws;
  const long SZ = 2097152;  // 2*8*2048*64
  u16* Qw = ws;
  u16* Kw = ws + SZ;
  u16* Vtw = ws + 2 * SZ;
  u16* Ow = ws + 3 * SZ;
  u16* WqkT = ws + 4 * SZ;
  u16* WvT = WqkT + 524288;
  u16* WoutT = WvT + 262144;
  u16* x1b = WoutT + 262144;
  u16* x2b = x1b + SZ;

  wprep<<<3072, 256, 0, stream>>>(Wqk, Wv, Wout, x1, x2, WqkT, WvT, WoutT, x1b, x2b);
  qkv_gemm<<<384, 256, 0, stream>>>(x1b, x2b, WqkT, WvT, Qw, Kw, Vtw);
  attn<<<512, 256, 0, stream>>>(Qw, Kw, Vtw, Ow);
  out_gemm<<<256, 256, 0, stream>>>(Ow, WoutT, out, bout);
}

// Round 4
// 127.361 us; speedup vs baseline: 6.2690x; 6.2690x over previous
//
#include <hip/hip_runtime.h>

typedef short bf16x8 __attribute__((ext_vector_type(8)));
typedef short bf16x4 __attribute__((ext_vector_type(4)));
typedef float f32x4 __attribute__((ext_vector_type(4)));
typedef float f32x16 __attribute__((ext_vector_type(16)));
typedef unsigned short u16;
typedef unsigned int u32;
typedef u16 u16x8 __attribute__((ext_vector_type(8)));
typedef u16 u16x4 __attribute__((ext_vector_type(4)));

#define DEV __device__ __forceinline__

DEV u16 f2bf(float f) {
  unsigned u = __float_as_uint(f);
  u += 0x7fff + ((u >> 16) & 1);  // RNE (no NaN in this workload)
  return (u16)(u >> 16);
}

// pack 2 fp32 -> 2 bf16: single HW instruction (RNE)
DEV int cvtpk(float lo, float hi) {
  int r;
  asm("v_cvt_pk_bf16_f32 %0, %1, %2" : "=v"(r) : "v"(lo), "v"(hi));
  return r;
}

// fallback 3-op pack (round-half-up) for the non-PV8 path
DEV int pkbf(float lo, float hi) {
  return __builtin_amdgcn_perm(__float_as_uint(hi) + 0x8000u,
                               __float_as_uint(lo) + 0x8000u, 0x07060302u);
}

#define MFMA16(a, b, c) __builtin_amdgcn_mfma_f32_16x16x32_bf16(a, b, c, 0, 0, 0)
#define MFMA3216(a, b, c) __builtin_amdgcn_mfma_f32_32x32x16_bf16(a, b, c, 0, 0, 0)

#if __has_builtin(__builtin_amdgcn_mfma_f32_32x32x8bf16_1k)
#define HAVE_PV8 1
#define PVMFMA(a, b, c) __builtin_amdgcn_mfma_f32_32x32x8bf16_1k(a, b, c, 0, 0, 0)
#else
#define HAVE_PV8 0
#endif

#if __has_builtin(__builtin_amdgcn_exp2f)
#define QSCALE 0.18033688011112042f  // 0.125 * log2(e)
#define EXPFN(x) __builtin_amdgcn_exp2f(x)
#else
#define QSCALE 0.125f
#define EXPFN(x) __expf(x)
#endif

#define GLD16(gp, lp)                                                     \
  __builtin_amdgcn_global_load_lds(                                       \
      (const __attribute__((address_space(1))) u32*)(gp),                 \
      (__attribute__((address_space(3))) u32*)(lp), 16, 0, 0)

// ---------------------------------------------------------------------------
// wprep (R1 version): transpose+convert weights; pre-convert x1/x2 to bf16.
// ---------------------------------------------------------------------------
__global__ __launch_bounds__(256) void wprep(
    const float* __restrict__ Wqk, const float* __restrict__ Wv,
    const float* __restrict__ Wout,
    const float* __restrict__ x1, const float* __restrict__ x2,
    u16* __restrict__ WqkT, u16* __restrict__ WvT, u16* __restrict__ WoutT,
    u16* __restrict__ x1b, u16* __restrict__ x2b) {
  __shared__ float tf[32][33];
  int bx = blockIdx.x, t = threadIdx.x;
  if (bx >= 1024) {
    int id = bx - 1024;  // 0..2047
    const float* src = id < 1024 ? x1 : x2;
    u16* dst = id < 1024 ? x1b : x2b;
    long base = (long)(id & 1023) * 2048 + t * 8;
    float4 f0 = *(const float4*)(src + base);
    float4 f1 = *(const float4*)(src + base + 4);
    u16x8 o;
    o[0] = f2bf(f0.x); o[1] = f2bf(f0.y); o[2] = f2bf(f0.z); o[3] = f2bf(f0.w);
    o[4] = f2bf(f1.x); o[5] = f2bf(f1.y); o[6] = f2bf(f1.z); o[7] = f2bf(f1.w);
    *(u16x8*)(dst + base) = o;
    return;
  }
  const float* src; u16* dst; int Ncols; int id;
  if (bx < 512)      { id = bx;       src = Wqk;  dst = WqkT;  Ncols = 1024; }
  else if (bx < 768) { id = bx - 512; src = Wv;   dst = WvT;   Ncols = 512; }
  else               { id = bx - 768; src = Wout; dst = WoutT; Ncols = 512; }
  int tilesPerRow = Ncols >> 5;
  int tr = id / tilesPerRow, tc = id % tilesPerRow;
  int r0 = tr * 32, c0 = tc * 32;
  {
    int r = t >> 3, c4 = (t & 7) * 4;
    float4 v = *(const float4*)(src + (long)(r0 + r) * Ncols + c0 + c4);
    tf[r][c4] = v.x; tf[r][c4 + 1] = v.y; tf[r][c4 + 2] = v.z; tf[r][c4 + 3] = v.w;
  }
  __syncthreads();
  {
    int c = t >> 3, r4 = (t & 7) * 4;
    u16x4 o;
    o[0] = f2bf(tf[r4][c]); o[1] = f2bf(tf[r4 + 1][c]);
    o[2] = f2bf(tf[r4 + 2][c]); o[3] = f2bf(tf[r4 + 3][c]);
    *(u16x4*)(dst + (long)(c0 + c) * 512 + r0 + r4) = o;
  }
}

// ---------------------------------------------------------------------------
// Fused QKV GEMM (R1 version — reg-staged, 128x64 tiles, grid 768; measured
// best of the variants tried so far).
// ---------------------------------------------------------------------------
__global__ __launch_bounds__(256) void qkv_gemm(
    const u16* __restrict__ x1b, const u16* __restrict__ x2b,
    const u16* __restrict__ WqkT, const u16* __restrict__ WvT,
    u16* __restrict__ out_q, u16* __restrict__ out_k, u16* __restrict__ out_vt) {
  __shared__ u16 sA[2][128 * 40];
  __shared__ u16 sB[2][64 * 40];
  int bx = blockIdx.x, t = threadIdx.x;
  bool isQ = bx < 256;
  int bx2 = isQ ? bx : bx - 256;
  const u16* Ap = isQ ? x2b : x1b;
  const u16* BT = isQ ? WvT : WqkT;
  int m0 = (bx2 & 31) * 128, n0 = (bx2 >> 5) * 64;
  int w = t >> 6, l = t & 63, lm = l & 15, lq = l >> 4;

  f32x4 zero = {0.f, 0.f, 0.f, 0.f};
  f32x4 acc[2][4];
#pragma unroll
  for (int i = 0; i < 2; ++i)
#pragma unroll
    for (int j = 0; j < 4; ++j) acc[i][j] = zero;

  int sm = t >> 2;
  int skc = (t & 3) * 8;
  const u16* gA = Ap + (long)(m0 + sm) * 512 + skc;
  const u16* gB = BT + (long)(n0 + sm) * 512 + skc;

  bf16x8 a0 = *(const bf16x8*)(gA);
  bf16x8 a1 = *(const bf16x8*)(gA + 64 * 512);
  bf16x8 b0 = *(const bf16x8*)(gB);
  *(bf16x8*)(sA[0] + sm * 40 + skc) = a0;
  *(bf16x8*)(sA[0] + (sm + 64) * 40 + skc) = a1;
  *(bf16x8*)(sB[0] + sm * 40 + skc) = b0;
  __syncthreads();

  for (int kt = 0; kt < 16; ++kt) {
    int cur = kt & 1;
    if (kt < 15) {
      a0 = *(const bf16x8*)(gA + (kt + 1) * 32);
      a1 = *(const bf16x8*)(gA + 64 * 512 + (kt + 1) * 32);
      b0 = *(const bf16x8*)(gB + (kt + 1) * 32);
    }
    bf16x8 af[2], bfr[4];
    af[0] = *(const bf16x8*)(sA[cur] + (w * 32 + lm) * 40 + lq * 8);
    af[1] = *(const bf16x8*)(sA[cur] + (w * 32 + 16 + lm) * 40 + lq * 8);
#pragma unroll
    for (int s = 0; s < 4; ++s)
      bfr[s] = *(const bf16x8*)(sB[cur] + (s * 16 + lm) * 40 + lq * 8);
#pragma unroll
    for (int ms = 0; ms < 2; ++ms)
#pragma unroll
      for (int s = 0; s < 4; ++s)
        acc[ms][s] = MFMA16(af[ms], bfr[s], acc[ms][s]);
    if (kt < 15) {
      int nxt = 1 - cur;
      *(bf16x8*)(sA[nxt] + sm * 40 + skc) = a0;
      *(bf16x8*)(sA[nxt] + (sm + 64) * 40 + skc) = a1;
      *(bf16x8*)(sB[nxt] + sm * 40 + skc) = b0;
    }
    __syncthreads();
  }

#pragma unroll
  for (int ms = 0; ms < 2; ++ms) {
    int gmBase = m0 + w * 32 + ms * 16 + lq * 4;
#pragma unroll
    for (int s = 0; s < 4; ++s) {
      int gc = n0 + s * 16 + lm;
      int b = gmBase >> 11, n = gmBase & 2047;
      if (isQ) {
#pragma unroll
        for (int r = 0; r < 4; ++r)
          out_q[(((long)(b << 3) + (gc >> 6)) * 2048 + n + r) * 64 + (gc & 63)] =
              f2bf(acc[ms][s][r] * QSCALE);
      } else if (gc < 512) {
#pragma unroll
        for (int r = 0; r < 4; ++r)
          out_k[(((long)(b << 3) + (gc >> 6)) * 2048 + n + r) * 64 + (gc & 63)] =
              f2bf(acc[ms][s][r]);
      } else {
        int c = gc - 512, h = c >> 6, d = c & 63;
        u16x4 vv;
#pragma unroll
        for (int r = 0; r < 4; ++r) vv[r] = f2bf(acc[ms][s][r]);
        *(u16x4*)(out_vt + (((long)(b << 3) + h) * 64 + d) * 2048 + n) = vv;
      }
    }
  }
}

// ---------------------------------------------------------------------------
// Attention v6: dbuf staging as R1 + VALU diet:
//  - QK: 4 MFMAs chained into ONE accumulator seeded by a persistent zero
//    vector (removes 32 zero-inits + 16 st1+st2 adds per kt2)
//  - P pack via single v_cvt_pk_bf16_f32 (was 3 ops per pair)
//  - tree-summed dacc, setprio around MFMA clusters
// ---------------------------------------------------------------------------
__global__ __launch_bounds__(256, 2) void attn(
    const u16* __restrict__ Q, const u16* __restrict__ K,
    const u16* __restrict__ Vt, u16* __restrict__ O) {
  int id = blockIdx.x;
  int bh = id & 15, qt = id >> 4;
  int b = bh >> 3, h = bh & 7;
  const u16* Kh = K + (long)bh * 2048 * 64;
  const u16* Vh = Vt + (long)bh * 64 * 2048;
  int t = threadIdx.x, w = t >> 6, lane = t & 63, ln = lane & 31, hi = lane >> 5;
  int g = w & 1, kh = w >> 1;

  __shared__ u16 smem[2][2][2][4096];  // [buf][K/V][kh][64x64 swizzled]

  bf16x8 qf[4];
  {
    const u16* qp = Q + (long)bh * 2048 * 64 + (long)(qt * 64 + g * 32 + ln) * 64 + hi * 8;
#pragma unroll
    for (int dc = 0; dc < 4; ++dc) qf[dc] = *(const bf16x8*)(qp + dc * 16);
  }

  f32x16 accO[2];
#pragma unroll
  for (int dt = 0; dt < 2; ++dt)
#pragma unroll
    for (int i = 0; i < 16; ++i) accO[dt][i] = 0.f;
  float dacc = 0.f;

  f32x16 fz;  // persistent zero C-operand for the QK chain
#pragma unroll
  for (int i = 0; i < 16; ++i) fz[i] = 0.f;

  int lrow = lane >> 3;
  int swz = ((lane & 7) ^ lrow) * 8;
  const u16* gKl = Kh + (long)(kh * 1024 + g * 32 + lrow) * 64 + swz;
  const u16* gVl = Vh + (long)(g * 32 + lrow) * 2048 + kh * 1024 + swz;

  auto stage = [&](int jt, int buf) {
    u16* sK = smem[buf][0][kh];
    u16* sV = smem[buf][1][kh];
    const u16* gk = gKl + (long)jt * 4096;
    const u16* gv = gVl + jt * 64;
#pragma unroll
    for (int i = 0; i < 4; ++i) {
      GLD16(gk + i * 512, sK + (g * 32 + i * 8) * 64);
      GLD16(gv + (long)i * 16384, sV + (g * 32 + i * 8) * 64);
    }
  };

  stage(0, 0);
  __syncthreads();

  int swl = ln & 7;
  for (int jt = 0; jt < 16; ++jt) {
    int cur = jt & 1;
    if (jt < 15) stage(jt + 1, cur ^ 1);  // issue next-tile DMA before compute
    const u16* sKh = smem[cur][0][kh];
    const u16* sVh = smem[cur][1][kh];
#pragma unroll
    for (int kt2 = 0; kt2 < 2; ++kt2) {
      int rowK = (kt2 * 32 + ln) * 64;
      bf16x8 kf0 = *(const bf16x8*)(sKh + rowK + ((0 * 2 + hi) ^ swl) * 8);
      bf16x8 kf1 = *(const bf16x8*)(sKh + rowK + ((1 * 2 + hi) ^ swl) * 8);
      bf16x8 kf2 = *(const bf16x8*)(sKh + rowK + ((2 * 2 + hi) ^ swl) * 8);
      bf16x8 kf3 = *(const bf16x8*)(sKh + rowK + ((3 * 2 + hi) ^ swl) * 8);
      __builtin_amdgcn_s_setprio(1);
      f32x16 st = MFMA3216(kf0, qf[0], fz);
      st = MFMA3216(kf1, qf[1], st);
      st = MFMA3216(kf2, qf[2], st);
      st = MFMA3216(kf3, qf[3], st);
      __builtin_amdgcn_s_setprio(0);
      float p[16];
#pragma unroll
      for (int i = 0; i < 16; ++i) p[i] = EXPFN(st[i]);
      float q0 = (p[0] + p[1]) + (p[2] + p[3]);
      float q1 = (p[4] + p[5]) + (p[6] + p[7]);
      float q2 = (p[8] + p[9]) + (p[10] + p[11]);
      float q3 = (p[12] + p[13]) + (p[14] + p[15]);
      dacc += (q0 + q1) + (q2 + q3);
#if HAVE_PV8
      __builtin_amdgcn_s_setprio(1);
#pragma unroll
      for (int c = 0; c < 4; ++c) {
        union { int2 i2; bf16x4 v; } u;
        u.i2.x = cvtpk(p[c * 4 + 0], p[c * 4 + 1]);
        u.i2.y = cvtpk(p[c * 4 + 2], p[c * 4 + 3]);
#pragma unroll
        for (int dt = 0; dt < 2; ++dt) {
          bf16x4 vf = *(const bf16x4*)(sVh + (dt * 32 + ln) * 64 +
                                       (((kt2 * 4 + c) ^ swl) * 8) + hi * 4);
          accO[dt] = PVMFMA(vf, u.v, accO[dt]);
        }
      }
      __builtin_amdgcn_s_setprio(0);
#else
      __builtin_amdgcn_s_setprio(1);
#pragma unroll
      for (int c2 = 0; c2 < 2; ++c2) {
        int o0x = pkbf(p[c2 * 8 + 0], p[c2 * 8 + 1]);
        int o0y = pkbf(p[c2 * 8 + 2], p[c2 * 8 + 3]);
        int o1x = pkbf(p[c2 * 8 + 4], p[c2 * 8 + 5]);
        int o1y = pkbf(p[c2 * 8 + 6], p[c2 * 8 + 7]);
        int s0x = __shfl_xor(o0x, 32), s0y = __shfl_xor(o0y, 32);
        int s1x = __shfl_xor(o1x, 32), s1y = __shfl_xor(o1y, 32);
        union { int4 i4; bf16x8 v; } u;
        if (hi) { u.i4.x = s1x; u.i4.y = s1y; u.i4.z = o1x; u.i4.w = o1y; }
        else    { u.i4.x = o0x; u.i4.y = o0y; u.i4.z = s0x; u.i4.w = s0y; }
#pragma unroll
        for (int dt = 0; dt < 2; ++dt) {
          bf16x8 vf = *(const bf16x8*)(sVh + (dt * 32 + ln) * 64 +
                                       (((kt2 * 4 + c2 * 2 + hi) ^ swl) * 8));
          accO[dt] = MFMA3216(vf, u.v, accO[dt]);
        }
      }
      __builtin_amdgcn_s_setprio(0);
#endif
    }
    __syncthreads();  // syncs consumers of buf[cur] AND drains this wave's DMA
  }

  // combine key-halves via LDS scratch (aliases smem; loop ended on a barrier)
  float* cb = (float*)&smem[0][0][0][0];
  float* base = cb + g * 2112;
  if (kh == 1) {
#pragma unroll
    for (int dt = 0; dt < 2; ++dt)
#pragma unroll
      for (int i = 0; i < 16; ++i)
        base[(dt * 16 + i) * 64 + hi * 32 + ln] = accO[dt][i];
    base[2048 + hi * 32 + ln] = dacc;
  }
  __syncthreads();
  if (kh == 0) {
#pragma unroll
    for (int dt = 0; dt < 2; ++dt)
#pragma unroll
      for (int i = 0; i < 16; ++i)
        accO[dt][i] += base[(dt * 16 + i) * 64 + hi * 32 + ln];
    dacc += base[2048 + hi * 32 + ln];
    dacc += __shfl_xor(dacc, 32);
    float inv = 1.f / dacc;

    u16* Ob = O + ((long)b * 2048 + qt * 64 + g * 32 + ln) * 512 + h * 64;
#pragma unroll
    for (int dt = 0; dt < 2; ++dt)
#pragma unroll
      for (int gq = 0; gq < 4; ++gq) {
        u16x4 o;
#pragma unroll
        for (int rr = 0; rr < 4; ++rr) o[rr] = f2bf(accO[dt][gq * 4 + rr] * inv);
        *(u16x4*)(Ob + dt * 32 + gq * 8 + hi * 4) = o;
      }
  }
}

// ---------------------------------------------------------------------------
// out GEMM (R1 version — 128 thr, 64x32 tiles, grid 1024).
// ---------------------------------------------------------------------------
__global__ __launch_bounds__(128) void out_gemm(
    const u16* __restrict__ A, const u16* __restrict__ BT,
    float* __restrict__ out_f, const float* __restrict__ bias) {
  __shared__ u16 sA[2][64 * 40];
  __shared__ u16 sB[2][32 * 40];
  int t = threadIdx.x, bx = blockIdx.x;
  int m0 = (bx & 63) * 64, n0 = (bx >> 6) * 32;
  int w = t >> 6, l = t & 63, lm = l & 15, lq = l >> 4;

  f32x4 zero = {0.f, 0.f, 0.f, 0.f};
  f32x4 acc[2][2];
#pragma unroll
  for (int i = 0; i < 2; ++i)
#pragma unroll
    for (int j = 0; j < 2; ++j) acc[i][j] = zero;

  int ar = t >> 1, akc = (t & 1) * 16;
  int br = t >> 2, bkc = (t & 3) * 8;
  const u16* gA = A + (long)(m0 + ar) * 512 + akc;
  const u16* gB = BT + (long)(n0 + br) * 512 + bkc;

  bf16x8 a0 = *(const bf16x8*)(gA);
  bf16x8 a1 = *(const bf16x8*)(gA + 8);
  bf16x8 b0 = *(const bf16x8*)(gB);
  *(bf16x8*)(sA[0] + ar * 40 + akc) = a0;
  *(bf16x8*)(sA[0] + ar * 40 + akc + 8) = a1;
  *(bf16x8*)(sB[0] + br * 40 + bkc) = b0;
  __syncthreads();

  for (int kt = 0; kt < 16; ++kt) {
    int cur = kt & 1;
    if (kt < 15) {
      a0 = *(const bf16x8*)(gA + (kt + 1) * 32);
      a1 = *(const bf16x8*)(gA + (kt + 1) * 32 + 8);
      b0 = *(const bf16x8*)(gB + (kt + 1) * 32);
    }
    bf16x8 af[2], bfr[2];
    af[0] = *(const bf16x8*)(sA[cur] + (w * 32 + lm) * 40 + lq * 8);
    af[1] = *(const bf16x8*)(sA[cur] + (w * 32 + 16 + lm) * 40 + lq * 8);
    bfr[0] = *(const bf16x8*)(sB[cur] + (lm)*40 + lq * 8);
    bfr[1] = *(const bf16x8*)(sB[cur] + (16 + lm) * 40 + lq * 8);
#pragma unroll
    for (int ms = 0; ms < 2; ++ms)
#pragma unroll
      for (int s = 0; s < 2; ++s)
        acc[ms][s] = MFMA16(af[ms], bfr[s], acc[ms][s]);
    if (kt < 15) {
      int nxt = 1 - cur;
      *(bf16x8*)(sA[nxt] + ar * 40 + akc) = a0;
      *(bf16x8*)(sA[nxt] + ar * 40 + akc + 8) = a1;
      *(bf16x8*)(sB[nxt] + br * 40 + bkc) = b0;
    }
    __syncthreads();
  }

#pragma unroll
  for (int ms = 0; ms < 2; ++ms) {
    int gmBase = m0 + w * 32 + ms * 16 + lq * 4;
#pragma unroll
    for (int s = 0; s < 2; ++s) {
      int gc = n0 + s * 16 + lm;
      float bv = bias[gc];
#pragma unroll
      for (int r = 0; r < 4; ++r)
        out_f[(long)(gmBase + r) * 512 + gc] = acc[ms][s][r] + bv;
    }
  }
}

// ---------------------------------------------------------------------------
extern "C" void kernel_launch(void* const* d_in, const int* in_sizes, int n_in,
                              void* d_out, int out_size, void* d_ws, size_t ws_size,
                              hipStream_t stream) {
  const float* x1 = (const float*)d_in[0];
  const float* x2 = (const float*)d_in[1];
  const float* Wqk = (const float*)d_in[2];
  const float* Wv = (const float*)d_in[3];
  const float* Wout = (const float*)d_in[4];
  const float* bout = (const float*)d_in[5];
  float* out = (float*)d_out;

  u16* ws = (u16*)d_ws;
  const long SZ = 2097152;  // 2*8*2048*64
  u16* Qw = ws;
  u16* Kw = ws + SZ;
  u16* Vtw = ws + 2 * SZ;
  u16* Ow = ws + 3 * SZ;
  u16* WqkT = ws + 4 * SZ;
  u16* WvT = WqkT + 524288;
  u16* WoutT = WvT + 262144;
  u16* x1b = WoutT + 262144;
  u16* x2b = x1b + SZ;

  wprep<<<3072, 256, 0, stream>>>(Wqk, Wv, Wout, x1, x2, WqkT, WvT, WoutT, x1b, x2b);
  qkv_gemm<<<768, 256, 0, stream>>>(x1b, x2b, WqkT, WvT, Qw, Kw, Vtw);
  attn<<<512, 256, 0, stream>>>(Qw, Kw, Vtw, Ow);
  out_gemm<<<1024, 128, 0, stream>>>(Ow, WoutT, out, bout);
}

// Round 5
// 126.595 us; speedup vs baseline: 6.3070x; 1.0060x over previous
//
#include <hip/hip_runtime.h>

typedef short bf16x8 __attribute__((ext_vector_type(8)));
typedef short bf16x4 __attribute__((ext_vector_type(4)));
typedef float f32x4 __attribute__((ext_vector_type(4)));
typedef float f32x16 __attribute__((ext_vector_type(16)));
typedef unsigned short u16;
typedef unsigned int u32;
typedef u16 u16x8 __attribute__((ext_vector_type(8)));
typedef u16 u16x4 __attribute__((ext_vector_type(4)));

#define DEV __device__ __forceinline__

DEV u16 f2bf(float f) {
  unsigned u = __float_as_uint(f);
  u += 0x7fff + ((u >> 16) & 1);  // RNE (no NaN in this workload)
  return (u16)(u >> 16);
}

// pack 2 fp32 -> 2 bf16: single HW instruction (RNE); lo -> low 16 bits
DEV int cvtpk(float lo, float hi) {
  int r;
  asm("v_cvt_pk_bf16_f32 %0, %1, %2" : "=v"(r) : "v"(lo), "v"(hi));
  return r;
}

// fallback 3-op pack (round-half-up) for the non-PV8 path
DEV int pkbf(float lo, float hi) {
  return __builtin_amdgcn_perm(__float_as_uint(hi) + 0x8000u,
                               __float_as_uint(lo) + 0x8000u, 0x07060302u);
}

#define MFMA16(a, b, c) __builtin_amdgcn_mfma_f32_16x16x32_bf16(a, b, c, 0, 0, 0)
#define MFMA3216(a, b, c) __builtin_amdgcn_mfma_f32_32x32x16_bf16(a, b, c, 0, 0, 0)

#if __has_builtin(__builtin_amdgcn_mfma_f32_32x32x8bf16_1k)
#define HAVE_PV8 1
#define PVMFMA(a, b, c) __builtin_amdgcn_mfma_f32_32x32x8bf16_1k(a, b, c, 0, 0, 0)
#else
#define HAVE_PV8 0
#endif

#if __has_builtin(__builtin_amdgcn_exp2f)
#define QSCALE 0.18033688011112042f  // 0.125 * log2(e)
#define EXPFN(x) __builtin_amdgcn_exp2f(x)
#else
#define QSCALE 0.125f
#define EXPFN(x) __expf(x)
#endif

#define GLD16(gp, lp)                                                     \
  __builtin_amdgcn_global_load_lds(                                       \
      (const __attribute__((address_space(1))) u32*)(gp),                 \
      (__attribute__((address_space(3))) u32*)(lp), 16, 0, 0)

// ---------------------------------------------------------------------------
// wprep: transpose+convert WEIGHTS only (x pre-convert removed — qkv now
// consumes x1/x2 f32 directly via global_load_lds). 1024 blocks.
// ---------------------------------------------------------------------------
__global__ __launch_bounds__(256) void wprep(
    const float* __restrict__ Wqk, const float* __restrict__ Wv,
    const float* __restrict__ Wout,
    u16* __restrict__ WqkT, u16* __restrict__ WvT, u16* __restrict__ WoutT) {
  __shared__ float tf[32][33];
  int bx = blockIdx.x, t = threadIdx.x;
  const float* src; u16* dst; int Ncols; int id;
  if (bx < 512)      { id = bx;       src = Wqk;  dst = WqkT;  Ncols = 1024; }
  else if (bx < 768) { id = bx - 512; src = Wv;   dst = WvT;   Ncols = 512; }
  else               { id = bx - 768; src = Wout; dst = WoutT; Ncols = 512; }
  int tilesPerRow = Ncols >> 5;
  int tr = id / tilesPerRow, tc = id % tilesPerRow;
  int r0 = tr * 32, c0 = tc * 32;
  {
    int r = t >> 3, c4 = (t & 7) * 4;
    float4 v = *(const float4*)(src + (long)(r0 + r) * Ncols + c0 + c4);
    tf[r][c4] = v.x; tf[r][c4 + 1] = v.y; tf[r][c4 + 2] = v.z; tf[r][c4 + 3] = v.w;
  }
  __syncthreads();
  {
    int c = t >> 3, r4 = (t & 7) * 4;
    u16x4 o;
    o[0] = f2bf(tf[r4][c]); o[1] = f2bf(tf[r4 + 1][c]);
    o[2] = f2bf(tf[r4 + 2][c]); o[3] = f2bf(tf[r4 + 3][c]);
    *(u16x4*)(dst + (long)(c0 + c) * 512 + r0 + r4) = o;
  }
}

// ---------------------------------------------------------------------------
// Fused QKV GEMM v4: A (x1/x2) staged as RAW F32 via global_load_lds into
// XOR-swizzled LDS (zero staging VALU / VGPR / ds_writes; each wave stages
// and consumes its own 32 rows). f32->bf16 at frag-read time via 8 cvtpk.
// Swizzle: row r, stored 16B-chunk p holds global chunk p^(r&7); frag read
// of chunk q reads position q^(r&7) -> conflict-free (banks fully spread).
// B (weights, bf16) stays reg-staged into padded-40 LDS as before.
// LDS 42 KB -> 3 blocks/CU, grid 768 = exactly resident.
// ---------------------------------------------------------------------------
__global__ __launch_bounds__(256) void qkv_gemm(
    const float* __restrict__ x1, const float* __restrict__ x2,
    const u16* __restrict__ WqkT, const u16* __restrict__ WvT,
    u16* __restrict__ out_q, u16* __restrict__ out_k, u16* __restrict__ out_vt) {
  __shared__ __align__(16) float sA32[2][128 * 32];
  __shared__ __align__(16) u16 sB[2][64 * 40];
  int bx = blockIdx.x, t = threadIdx.x;
  bool isQ = bx < 256;
  int bx2 = isQ ? bx : bx - 256;
  const float* Ap = isQ ? x2 : x1;
  const u16* BT = isQ ? WvT : WqkT;
  int m0 = (bx2 & 31) * 128, n0 = (bx2 >> 5) * 64;
  int w = t >> 6, l = t & 63, lm = l & 15, lq = l >> 4;

  f32x4 zero = {0.f, 0.f, 0.f, 0.f};
  f32x4 acc[2][4];
#pragma unroll
  for (int i = 0; i < 2; ++i)
#pragma unroll
    for (int j = 0; j < 4; ++j) acc[i][j] = zero;

  // A DMA source (per lane): wave w stages rows w*32..w*32+31.
  // lane l: row offset l>>3 within 8-row group, stored chunk l&7 holds
  // global 16B chunk (l&7)^(l>>3)  (row&7 == l>>3 for 8-row groups).
  int dr = l >> 3;
  int dc = (l & 7) ^ dr;
  const float* gAsrc = Ap + (long)(m0 + w * 32 + dr) * 512 + dc * 4;

  auto stageA = [&](int kt, int buf) {
#pragma unroll
    for (int i = 0; i < 4; ++i)
      GLD16(gAsrc + kt * 32 + i * 8 * 512, sA32[buf] + (w * 32 + i * 8) * 32);
  };

  // B reg-staged (unchanged from R1)
  int sm = t >> 2;
  int skc = (t & 3) * 8;
  const u16* gB = BT + (long)(n0 + sm) * 512 + skc;

  stageA(0, 0);
  bf16x8 b0 = *(const bf16x8*)(gB);
  *(bf16x8*)(sB[0] + sm * 40 + skc) = b0;
  __syncthreads();

  int sw7 = lm & 7;
  for (int kt = 0; kt < 16; ++kt) {
    int cur = kt & 1;
    if (kt < 15) {
      stageA(kt + 1, cur ^ 1);               // async DMA into next buffer
      b0 = *(const bf16x8*)(gB + (kt + 1) * 32);
    }
    bf16x8 af[2], bfr[4];
#pragma unroll
    for (int ms = 0; ms < 2; ++ms) {
      const float* rp = sA32[cur] + (w * 32 + ms * 16 + lm) * 32;
      f32x4 c0 = *(const f32x4*)(rp + ((2 * lq) ^ sw7) * 4);
      f32x4 c1 = *(const f32x4*)(rp + ((2 * lq + 1) ^ sw7) * 4);
      union { int4 i; bf16x8 v; } ua;
      ua.i.x = cvtpk(c0[0], c0[1]);
      ua.i.y = cvtpk(c0[2], c0[3]);
      ua.i.z = cvtpk(c1[0], c1[1]);
      ua.i.w = cvtpk(c1[2], c1[3]);
      af[ms] = ua.v;
    }
#pragma unroll
    for (int s = 0; s < 4; ++s)
      bfr[s] = *(const bf16x8*)(sB[cur] + (s * 16 + lm) * 40 + lq * 8);
#pragma unroll
    for (int ms = 0; ms < 2; ++ms)
#pragma unroll
      for (int s = 0; s < 4; ++s)
        acc[ms][s] = MFMA16(af[ms], bfr[s], acc[ms][s]);
    if (kt < 15)
      *(bf16x8*)(sB[cur ^ 1] + sm * 40 + skc) = b0;
    __syncthreads();  // drains own GLD16 vmcnt + publishes B writes
  }

#pragma unroll
  for (int ms = 0; ms < 2; ++ms) {
    int gmBase = m0 + w * 32 + ms * 16 + lq * 4;
#pragma unroll
    for (int s = 0; s < 4; ++s) {
      int gc = n0 + s * 16 + lm;
      int b = gmBase >> 11, n = gmBase & 2047;
      if (isQ) {
#pragma unroll
        for (int r = 0; r < 4; ++r)
          out_q[(((long)(b << 3) + (gc >> 6)) * 2048 + n + r) * 64 + (gc & 63)] =
              f2bf(acc[ms][s][r] * QSCALE);
      } else if (gc < 512) {
#pragma unroll
        for (int r = 0; r < 4; ++r)
          out_k[(((long)(b << 3) + (gc >> 6)) * 2048 + n + r) * 64 + (gc & 63)] =
              f2bf(acc[ms][s][r]);
      } else {
        int c = gc - 512, h = c >> 6, d = c & 63;
        u16x4 vv;
#pragma unroll
        for (int r = 0; r < 4; ++r) vv[r] = f2bf(acc[ms][s][r]);
        *(u16x4*)(out_vt + (((long)(b << 3) + h) * 64 + d) * 2048 + n) = vv;
      }
    }
  }
}

// ---------------------------------------------------------------------------
// Attention v6 (unchanged from R4): dbuf DMA staging, single-acc QK chain,
// cvtpk pack, tree dacc, setprio.
// ---------------------------------------------------------------------------
__global__ __launch_bounds__(256, 2) void attn(
    const u16* __restrict__ Q, const u16* __restrict__ K,
    const u16* __restrict__ Vt, u16* __restrict__ O) {
  int id = blockIdx.x;
  int bh = id & 15, qt = id >> 4;
  int b = bh >> 3, h = bh & 7;
  const u16* Kh = K + (long)bh * 2048 * 64;
  const u16* Vh = Vt + (long)bh * 64 * 2048;
  int t = threadIdx.x, w = t >> 6, lane = t & 63, ln = lane & 31, hi = lane >> 5;
  int g = w & 1, kh = w >> 1;

  __shared__ u16 smem[2][2][2][4096];  // [buf][K/V][kh][64x64 swizzled]

  bf16x8 qf[4];
  {
    const u16* qp = Q + (long)bh * 2048 * 64 + (long)(qt * 64 + g * 32 + ln) * 64 + hi * 8;
#pragma unroll
    for (int dc = 0; dc < 4; ++dc) qf[dc] = *(const bf16x8*)(qp + dc * 16);
  }

  f32x16 accO[2];
#pragma unroll
  for (int dt = 0; dt < 2; ++dt)
#pragma unroll
    for (int i = 0; i < 16; ++i) accO[dt][i] = 0.f;
  float dacc = 0.f;

  f32x16 fz;  // persistent zero C-operand for the QK chain
#pragma unroll
  for (int i = 0; i < 16; ++i) fz[i] = 0.f;

  int lrow = lane >> 3;
  int swz = ((lane & 7) ^ lrow) * 8;
  const u16* gKl = Kh + (long)(kh * 1024 + g * 32 + lrow) * 64 + swz;
  const u16* gVl = Vh + (long)(g * 32 + lrow) * 2048 + kh * 1024 + swz;

  auto stage = [&](int jt, int buf) {
    u16* sK = smem[buf][0][kh];
    u16* sV = smem[buf][1][kh];
    const u16* gk = gKl + (long)jt * 4096;
    const u16* gv = gVl + jt * 64;
#pragma unroll
    for (int i = 0; i < 4; ++i) {
      GLD16(gk + i * 512, sK + (g * 32 + i * 8) * 64);
      GLD16(gv + (long)i * 16384, sV + (g * 32 + i * 8) * 64);
    }
  };

  stage(0, 0);
  __syncthreads();

  int swl = ln & 7;
  for (int jt = 0; jt < 16; ++jt) {
    int cur = jt & 1;
    if (jt < 15) stage(jt + 1, cur ^ 1);  // issue next-tile DMA before compute
    const u16* sKh = smem[cur][0][kh];
    const u16* sVh = smem[cur][1][kh];
#pragma unroll
    for (int kt2 = 0; kt2 < 2; ++kt2) {
      int rowK = (kt2 * 32 + ln) * 64;
      bf16x8 kf0 = *(const bf16x8*)(sKh + rowK + ((0 * 2 + hi) ^ swl) * 8);
      bf16x8 kf1 = *(const bf16x8*)(sKh + rowK + ((1 * 2 + hi) ^ swl) * 8);
      bf16x8 kf2 = *(const bf16x8*)(sKh + rowK + ((2 * 2 + hi) ^ swl) * 8);
      bf16x8 kf3 = *(const bf16x8*)(sKh + rowK + ((3 * 2 + hi) ^ swl) * 8);
      __builtin_amdgcn_s_setprio(1);
      f32x16 st = MFMA3216(kf0, qf[0], fz);
      st = MFMA3216(kf1, qf[1], st);
      st = MFMA3216(kf2, qf[2], st);
      st = MFMA3216(kf3, qf[3], st);
      __builtin_amdgcn_s_setprio(0);
      float p[16];
#pragma unroll
      for (int i = 0; i < 16; ++i) p[i] = EXPFN(st[i]);
      float q0 = (p[0] + p[1]) + (p[2] + p[3]);
      float q1 = (p[4] + p[5]) + (p[6] + p[7]);
      float q2 = (p[8] + p[9]) + (p[10] + p[11]);
      float q3 = (p[12] + p[13]) + (p[14] + p[15]);
      dacc += (q0 + q1) + (q2 + q3);
#if HAVE_PV8
      __builtin_amdgcn_s_setprio(1);
#pragma unroll
      for (int c = 0; c < 4; ++c) {
        union { int2 i2; bf16x4 v; } u;
        u.i2.x = cvtpk(p[c * 4 + 0], p[c * 4 + 1]);
        u.i2.y = cvtpk(p[c * 4 + 2], p[c * 4 + 3]);
#pragma unroll
        for (int dt = 0; dt < 2; ++dt) {
          bf16x4 vf = *(const bf16x4*)(sVh + (dt * 32 + ln) * 64 +
                                       (((kt2 * 4 + c) ^ swl) * 8) + hi * 4);
          accO[dt] = PVMFMA(vf, u.v, accO[dt]);
        }
      }
      __builtin_amdgcn_s_setprio(0);
#else
      __builtin_amdgcn_s_setprio(1);
#pragma unroll
      for (int c2 = 0; c2 < 2; ++c2) {
        int o0x = pkbf(p[c2 * 8 + 0], p[c2 * 8 + 1]);
        int o0y = pkbf(p[c2 * 8 + 2], p[c2 * 8 + 3]);
        int o1x = pkbf(p[c2 * 8 + 4], p[c2 * 8 + 5]);
        int o1y = pkbf(p[c2 * 8 + 6], p[c2 * 8 + 7]);
        int s0x = __shfl_xor(o0x, 32), s0y = __shfl_xor(o0y, 32);
        int s1x = __shfl_xor(o1x, 32), s1y = __shfl_xor(o1y, 32);
        union { int4 i4; bf16x8 v; } u;
        if (hi) { u.i4.x = s1x; u.i4.y = s1y; u.i4.z = o1x; u.i4.w = o1y; }
        else    { u.i4.x = o0x; u.i4.y = o0y; u.i4.z = s0x; u.i4.w = s0y; }
#pragma unroll
        for (int dt = 0; dt < 2; ++dt) {
          bf16x8 vf = *(const bf16x8*)(sVh + (dt * 32 + ln) * 64 +
                                       (((kt2 * 4 + c2 * 2 + hi) ^ swl) * 8));
          accO[dt] = MFMA3216(vf, u.v, accO[dt]);
        }
      }
      __builtin_amdgcn_s_setprio(0);
#endif
    }
    __syncthreads();  // syncs consumers of buf[cur] AND drains this wave's DMA
  }

  // combine key-halves via LDS scratch (aliases smem; loop ended on a barrier)
  float* cb = (float*)&smem[0][0][0][0];
  float* base = cb + g * 2112;
  if (kh == 1) {
#pragma unroll
    for (int dt = 0; dt < 2; ++dt)
#pragma unroll
      for (int i = 0; i < 16; ++i)
        base[(dt * 16 + i) * 64 + hi * 32 + ln] = accO[dt][i];
    base[2048 + hi * 32 + ln] = dacc;
  }
  __syncthreads();
  if (kh == 0) {
#pragma unroll
    for (int dt = 0; dt < 2; ++dt)
#pragma unroll
      for (int i = 0; i < 16; ++i)
        accO[dt][i] += base[(dt * 16 + i) * 64 + hi * 32 + ln];
    dacc += base[2048 + hi * 32 + ln];
    dacc += __shfl_xor(dacc, 32);
    float inv = 1.f / dacc;

    u16* Ob = O + ((long)b * 2048 + qt * 64 + g * 32 + ln) * 512 + h * 64;
#pragma unroll
    for (int dt = 0; dt < 2; ++dt)
#pragma unroll
      for (int gq = 0; gq < 4; ++gq) {
        u16x4 o;
#pragma unroll
        for (int rr = 0; rr < 4; ++rr) o[rr] = f2bf(accO[dt][gq * 4 + rr] * inv);
        *(u16x4*)(Ob + dt * 32 + gq * 8 + hi * 4) = o;
      }
  }
}

// ---------------------------------------------------------------------------
// out GEMM (unchanged — 128 thr, 64x32 tiles, grid 1024).
// ---------------------------------------------------------------------------
__global__ __launch_bounds__(128) void out_gemm(
    const u16* __restrict__ A, const u16* __restrict__ BT,
    float* __restrict__ out_f, const float* __restrict__ bias) {
  __shared__ u16 sA[2][64 * 40];
  __shared__ u16 sB[2][32 * 40];
  int t = threadIdx.x, bx = blockIdx.x;
  int m0 = (bx & 63) * 64, n0 = (bx >> 6) * 32;
  int w = t >> 6, l = t & 63, lm = l & 15, lq = l >> 4;

  f32x4 zero = {0.f, 0.f, 0.f, 0.f};
  f32x4 acc[2][2];
#pragma unroll
  for (int i = 0; i < 2; ++i)
#pragma unroll
    for (int j = 0; j < 2; ++j) acc[i][j] = zero;

  int ar = t >> 1, akc = (t & 1) * 16;
  int br = t >> 2, bkc = (t & 3) * 8;
  const u16* gA = A + (long)(m0 + ar) * 512 + akc;
  const u16* gB = BT + (long)(n0 + br) * 512 + bkc;

  bf16x8 a0 = *(const bf16x8*)(gA);
  bf16x8 a1 = *(const bf16x8*)(gA + 8);
  bf16x8 b0 = *(const bf16x8*)(gB);
  *(bf16x8*)(sA[0] + ar * 40 + akc) = a0;
  *(bf16x8*)(sA[0] + ar * 40 + akc + 8) = a1;
  *(bf16x8*)(sB[0] + br * 40 + bkc) = b0;
  __syncthreads();

  for (int kt = 0; kt < 16; ++kt) {
    int cur = kt & 1;
    if (kt < 15) {
      a0 = *(const bf16x8*)(gA + (kt + 1) * 32);
      a1 = *(const bf16x8*)(gA + (kt + 1) * 32 + 8);
      b0 = *(const bf16x8*)(gB + (kt + 1) * 32);
    }
    bf16x8 af[2], bfr[2];
    af[0] = *(const bf16x8*)(sA[cur] + (w * 32 + lm) * 40 + lq * 8);
    af[1] = *(const bf16x8*)(sA[cur] + (w * 32 + 16 + lm) * 40 + lq * 8);
    bfr[0] = *(const bf16x8*)(sB[cur] + (lm)*40 + lq * 8);
    bfr[1] = *(const bf16x8*)(sB[cur] + (16 + lm) * 40 + lq * 8);
#pragma unroll
    for (int ms = 0; ms < 2; ++ms)
#pragma unroll
      for (int s = 0; s < 2; ++s)
        acc[ms][s] = MFMA16(af[ms], bfr[s], acc[ms][s]);
    if (kt < 15) {
      int nxt = 1 - cur;
      *(bf16x8*)(sA[nxt] + ar * 40 + akc) = a0;
      *(bf16x8*)(sA[nxt] + ar * 40 + akc + 8) = a1;
      *(bf16x8*)(sB[nxt] + br * 40 + bkc) = b0;
    }
    __syncthreads();
  }

#pragma unroll
  for (int ms = 0; ms < 2; ++ms) {
    int gmBase = m0 + w * 32 + ms * 16 + lq * 4;
#pragma unroll
    for (int s = 0; s < 2; ++s) {
      int gc = n0 + s * 16 + lm;
      float bv = bias[gc];
#pragma unroll
      for (int r = 0; r < 4; ++r)
        out_f[(long)(gmBase + r) * 512 + gc] = acc[ms][s][r] + bv;
    }
  }
}

// ---------------------------------------------------------------------------
extern "C" void kernel_launch(void* const* d_in, const int* in_sizes, int n_in,
                              void* d_out, int out_size, void* d_ws, size_t ws_size,
                              hipStream_t stream) {
  const float* x1 = (const float*)d_in[0];
  const float* x2 = (const float*)d_in[1];
  const float* Wqk = (const float*)d_in[2];
  const float* Wv = (const float*)d_in[3];
  const float* Wout = (const float*)d_in[4];
  const float* bout = (const float*)d_in[5];
  float* out = (float*)d_out;

  u16* ws = (u16*)d_ws;
  const long SZ = 2097152;  // 2*8*2048*64
  u16* Qw = ws;
  u16* Kw = ws + SZ;
  u16* Vtw = ws + 2 * SZ;
  u16* Ow = ws + 3 * SZ;
  u16* WqkT = ws + 4 * SZ;
  u16* WvT = WqkT + 524288;
  u16* WoutT = WvT + 262144;

  wprep<<<1024, 256, 0, stream>>>(Wqk, Wv, Wout, WqkT, WvT, WoutT);
  qkv_gemm<<<768, 256, 0, stream>>>(x1, x2, WqkT, WvT, Qw, Kw, Vtw);
  attn<<<512, 256, 0, stream>>>(Qw, Kw, Vtw, Ow);
  out_gemm<<<1024, 128, 0, stream>>>(Ow, WoutT, out, bout);
}